// Round 9
// baseline (231.110 us; speedup 1.0000x reference)
//
#include <hip/hip_runtime.h>

#define B_ 32
#define T_ 4096
#define C_ 256
#define R_ (B_*T_)
#define H1_ 128
#define H2_ 64

#define TB 64   // timestep rows per block in kernel 1

// output layout (floats), concatenated in reference return order
#define PROBS_OFF 0
#define TS_OFF  (R_*4)
#define SEG_OFF (TS_OFF + R_)
#define MI_OFF  (SEG_OFF + R_)
#define MC_OFF  (MI_OFF + R_)

// LDS float layout, 12544 floats = 50.2 KB -> 3 blocks/CU:
//   R0 [0..8448):      XS32 [32][260] (conv, two passes) -> H1S [64][132]
//   R1 [8448..10496):  W1S [16][128] linear               \ overlaid by
//   R2 [10496..11776): AC  [64][20]  (A chunk, 16 k)      / W2S [64][64]
#define XS_OFF  0
#define XS_P    260
#define H1S_OFF 0
#define H1S_P   132
#define W1S_OFF 8448
#define AC_OFF  10496
#define AC_P    20
#define W2S_OFF 8448
#define SMEMF   12544

__device__ __forceinline__ void fma4(float4& a, float s, const float4& b) {
  a.x = fmaf(s, b.x, a.x); a.y = fmaf(s, b.y, a.y);
  a.z = fmaf(s, b.z, a.z); a.w = fmaf(s, b.w, a.w);
}

__global__ __launch_bounds__(256, 3) void mlp_conv_kernel(
    const float* __restrict__ X, const float* __restrict__ W1, const float* __restrict__ b1,
    const float* __restrict__ W2, const float* __restrict__ b2,
    const float* __restrict__ W3, const float* __restrict__ b3,
    const float* __restrict__ CW, const float* __restrict__ CB,
    float* __restrict__ out)
{
  __shared__ float sm[SMEMF];
  const int tid  = threadIdx.x;
  const int l    = tid & 63;
  const int w    = tid >> 6;
  const int row0 = blockIdx.x * TB;
  const float4* Xf4 = (const float4*)X;

  // ---- prefetch W1 chunk 0 (16 k-rows) + A chunk 0 (64 rows x 16 k) ----
  float4 st0 = ((const float4*)W1)[tid];
  float4 st1 = ((const float4*)W1)[tid + 256];
  float4 sa0 = Xf4[(size_t)(row0 + (tid >> 2)) * 64 + (tid & 3)];

  // ---- conv1d (C->1, k=3, SAME) + sigmoid, two 32-row passes (R5 pattern) ----
  #pragma unroll
  for (int half = 0; half < 2; ++half) {
    if (half) __syncthreads();   // conv pass 0 reads done before restage
    #pragma unroll
    for (int i2 = 0; i2 < 8; ++i2) {
      int g = tid + 256 * i2;          // f4 index: 32*64 = 2048 total
      int r = g >> 6, m = g & 63;
      float4 v = *(const float4*)&X[(size_t)(row0 + half * 32 + r) * C_ + m * 4];
      *(float4*)&sm[XS_OFF + r * XS_P + m * 4] = v;
    }
    __syncthreads();
    const int rowi = w * 8 + (l & 7);
    const int p = l >> 3;                        // 0..7
    const int grow = row0 + half * 32 + rowi;
    const int tb = grow & (T_ - 1);              // t within its batch row
    float s = 0.f;
    #pragma unroll
    for (int cc = 0; cc < 8; ++cc) {
      const int c = p * 32 + cc * 4;
      float4 x0 = *(const float4*)&sm[XS_OFF + rowi * XS_P + c];
      float4 xm, xp;
      if (tb == 0)            xm = make_float4(0.f, 0.f, 0.f, 0.f);
      else if (rowi >= 1)     xm = *(const float4*)&sm[XS_OFF + (rowi - 1) * XS_P + c];
      else                    xm = *(const float4*)&X[(size_t)(grow - 1) * C_ + c];
      if (tb == T_ - 1)       xp = make_float4(0.f, 0.f, 0.f, 0.f);
      else if (rowi + 1 < 32) xp = *(const float4*)&sm[XS_OFF + (rowi + 1) * XS_P + c];
      else                    xp = *(const float4*)&X[(size_t)(grow + 1) * C_ + c];
      float4 wa = *(const float4*)&CW[c * 3 + 0];
      float4 wb = *(const float4*)&CW[c * 3 + 4];
      float4 wc = *(const float4*)&CW[c * 3 + 8];
      s += xm.x * wa.x + x0.x * wa.y + xp.x * wa.z;
      s += xm.y * wa.w + x0.y * wb.x + xp.y * wb.y;
      s += xm.z * wb.z + x0.z * wb.w + xp.z * wc.x;
      s += xm.w * wc.y + x0.w * wc.z + xp.w * wc.w;
    }
    s += __shfl_xor(s, 8);
    s += __shfl_xor(s, 16);
    s += __shfl_xor(s, 32);
    if (p == 0) out[TS_OFF + grow] = 1.f / (1.f + expf(-(s + CB[0])));
  }
  __syncthreads();   // conv done; R0 free (H1S later), W1S/AC writable

  // ---- GEMM1: (64x256)@(256x128), 8x4 per thread.
  //      A: AC[64][20] chunk (broadcast b128). B: W1S[16][128].
  //      Both staged global->reg->LDS with 1-chunk-ahead prefetch. ----
  const int rt = tid >> 5, ct = tid & 31;   // 8 row-groups x 32 col-groups
  const int rb = rt * 8;
  const int acq = (tid >> 2) * AC_P + (tid & 3) * 4;   // this thread's AC write slot
  float4 w2x;                                          // 4th reg for W2 prefetch
  float4 acc[8];
  #pragma unroll
  for (int r = 0; r < 8; ++r) acc[r] = make_float4(0.f, 0.f, 0.f, 0.f);

  for (int kc = 0; kc < 16; ++kc) {
    *(float4*)&sm[W1S_OFF + tid * 4]         = st0;
    *(float4*)&sm[W1S_OFF + (tid + 256) * 4] = st1;
    *(float4*)&sm[AC_OFF + acq]              = sa0;
    __syncthreads();
    if (kc + 1 < 16) {   // prefetch next W1 + A chunks (hidden under compute)
      const float* wp = W1 + (size_t)(kc + 1) * 2048;
      st0 = ((const float4*)wp)[tid];
      st1 = ((const float4*)wp)[tid + 256];
      sa0 = Xf4[(size_t)(row0 + (tid >> 2)) * 64 + (kc + 1) * 4 + (tid & 3)];
    } else {             // prefetch W2 chunk 0 (k-rows 0..63, 1024 f4)
      st0 = ((const float4*)W2)[tid];
      st1 = ((const float4*)W2)[tid + 256];
      sa0 = ((const float4*)W2)[tid + 512];
      w2x = ((const float4*)W2)[tid + 768];
    }
    #pragma unroll
    for (int k4 = 0; k4 < 4; ++k4) {
      float4 a0 = *(const float4*)&sm[AC_OFF + (rb + 0) * AC_P + k4 * 4];
      float4 a1 = *(const float4*)&sm[AC_OFF + (rb + 1) * AC_P + k4 * 4];
      float4 a2 = *(const float4*)&sm[AC_OFF + (rb + 2) * AC_P + k4 * 4];
      float4 a3 = *(const float4*)&sm[AC_OFF + (rb + 3) * AC_P + k4 * 4];
      float4 a4 = *(const float4*)&sm[AC_OFF + (rb + 4) * AC_P + k4 * 4];
      float4 a5 = *(const float4*)&sm[AC_OFF + (rb + 5) * AC_P + k4 * 4];
      float4 a6 = *(const float4*)&sm[AC_OFF + (rb + 6) * AC_P + k4 * 4];
      float4 a7 = *(const float4*)&sm[AC_OFF + (rb + 7) * AC_P + k4 * 4];
      float4 q0 = *(const float4*)&sm[W1S_OFF + (k4 * 4 + 0) * H1_ + ct * 4];
      float4 q1 = *(const float4*)&sm[W1S_OFF + (k4 * 4 + 1) * H1_ + ct * 4];
      float4 q2 = *(const float4*)&sm[W1S_OFF + (k4 * 4 + 2) * H1_ + ct * 4];
      float4 q3 = *(const float4*)&sm[W1S_OFF + (k4 * 4 + 3) * H1_ + ct * 4];
      fma4(acc[0], a0.x, q0); fma4(acc[0], a0.y, q1); fma4(acc[0], a0.z, q2); fma4(acc[0], a0.w, q3);
      fma4(acc[1], a1.x, q0); fma4(acc[1], a1.y, q1); fma4(acc[1], a1.z, q2); fma4(acc[1], a1.w, q3);
      fma4(acc[2], a2.x, q0); fma4(acc[2], a2.y, q1); fma4(acc[2], a2.z, q2); fma4(acc[2], a2.w, q3);
      fma4(acc[3], a3.x, q0); fma4(acc[3], a3.y, q1); fma4(acc[3], a3.z, q2); fma4(acc[3], a3.w, q3);
      fma4(acc[4], a4.x, q0); fma4(acc[4], a4.y, q1); fma4(acc[4], a4.z, q2); fma4(acc[4], a4.w, q3);
      fma4(acc[5], a5.x, q0); fma4(acc[5], a5.y, q1); fma4(acc[5], a5.z, q2); fma4(acc[5], a5.w, q3);
      fma4(acc[6], a6.x, q0); fma4(acc[6], a6.y, q1); fma4(acc[6], a6.z, q2); fma4(acc[6], a6.w, q3);
      fma4(acc[7], a7.x, q0); fma4(acc[7], a7.y, q1); fma4(acc[7], a7.z, q2); fma4(acc[7], a7.w, q3);
    }
    __syncthreads();   // all reads of this chunk done before next write
  }

  // ---- epilogue staging regs (W3/b3; latency hidden under H1 writes) ----
  const int rt2 = tid >> 4, ct2 = tid & 15;
  float4 w30 = ((const float4*)W3)[ct2 * 4 + 0];
  float4 w31 = ((const float4*)W3)[ct2 * 4 + 1];
  float4 w32 = ((const float4*)W3)[ct2 * 4 + 2];
  float4 w33 = ((const float4*)W3)[ct2 * 4 + 3];
  float4 b3v = *(const float4*)&b3[0];

  // ---- bias+relu -> H1S [64][132] (overlays XS32, dead) ----
  {
    float4 bb = ((const float4*)b1)[ct];
    #pragma unroll
    for (int r = 0; r < 8; ++r) {
      float4 h = acc[r];
      h.x = fmaxf(h.x + bb.x, 0.f); h.y = fmaxf(h.y + bb.y, 0.f);
      h.z = fmaxf(h.z + bb.z, 0.f); h.w = fmaxf(h.w + bb.w, 0.f);
      *(float4*)&sm[H1S_OFF + (rb + r) * H1S_P + ct * 4] = h;
    }
  }
  // W2 chunk 0 -> W2S [64][64] (overlays W1S/AC, dead)
  *(float4*)&sm[W2S_OFF + tid * 4]         = st0;
  *(float4*)&sm[W2S_OFF + (tid + 256) * 4] = st1;
  *(float4*)&sm[W2S_OFF + (tid + 512) * 4] = sa0;
  *(float4*)&sm[W2S_OFF + (tid + 768) * 4] = w2x;
  __syncthreads();

  // prefetch W2 chunk 1 (k-rows 64..127) — consumed after next barrier
  st0 = ((const float4*)W2)[tid + 1024];
  st1 = ((const float4*)W2)[tid + 1280];
  sa0 = ((const float4*)W2)[tid + 1536];
  w2x = ((const float4*)W2)[tid + 1792];

  // ---- GEMM2: (64x128)@(128x64), 4x4 per thread; W2 in two 64-k chunks ----
  float4 acc2[4];
  #pragma unroll
  for (int j = 0; j < 4; ++j) acc2[j] = make_float4(0.f, 0.f, 0.f, 0.f);
  #pragma unroll 4
  for (int k4 = 0; k4 < 16; ++k4) {          // k 0..63
    float4 a0 = *(const float4*)&sm[H1S_OFF + (rt2 * 4 + 0) * H1S_P + k4 * 4];
    float4 a1 = *(const float4*)&sm[H1S_OFF + (rt2 * 4 + 1) * H1S_P + k4 * 4];
    float4 a2 = *(const float4*)&sm[H1S_OFF + (rt2 * 4 + 2) * H1S_P + k4 * 4];
    float4 a3 = *(const float4*)&sm[H1S_OFF + (rt2 * 4 + 3) * H1S_P + k4 * 4];
    float4 q0 = *(const float4*)&sm[W2S_OFF + (k4 * 4 + 0) * H2_ + ct2 * 4];
    float4 q1 = *(const float4*)&sm[W2S_OFF + (k4 * 4 + 1) * H2_ + ct2 * 4];
    float4 q2 = *(const float4*)&sm[W2S_OFF + (k4 * 4 + 2) * H2_ + ct2 * 4];
    float4 q3 = *(const float4*)&sm[W2S_OFF + (k4 * 4 + 3) * H2_ + ct2 * 4];
    fma4(acc2[0], a0.x, q0); fma4(acc2[0], a0.y, q1); fma4(acc2[0], a0.z, q2); fma4(acc2[0], a0.w, q3);
    fma4(acc2[1], a1.x, q0); fma4(acc2[1], a1.y, q1); fma4(acc2[1], a1.z, q2); fma4(acc2[1], a1.w, q3);
    fma4(acc2[2], a2.x, q0); fma4(acc2[2], a2.y, q1); fma4(acc2[2], a2.z, q2); fma4(acc2[2], a2.w, q3);
    fma4(acc2[3], a3.x, q0); fma4(acc2[3], a3.y, q1); fma4(acc2[3], a3.z, q2); fma4(acc2[3], a3.w, q3);
  }
  __syncthreads();   // chunk-0 reads done
  *(float4*)&sm[W2S_OFF + tid * 4]         = st0;
  *(float4*)&sm[W2S_OFF + (tid + 256) * 4] = st1;
  *(float4*)&sm[W2S_OFF + (tid + 512) * 4] = sa0;
  *(float4*)&sm[W2S_OFF + (tid + 768) * 4] = w2x;
  __syncthreads();
  #pragma unroll 4
  for (int k4 = 16; k4 < 32; ++k4) {         // k 64..127
    float4 a0 = *(const float4*)&sm[H1S_OFF + (rt2 * 4 + 0) * H1S_P + k4 * 4];
    float4 a1 = *(const float4*)&sm[H1S_OFF + (rt2 * 4 + 1) * H1S_P + k4 * 4];
    float4 a2 = *(const float4*)&sm[H1S_OFF + (rt2 * 4 + 2) * H1S_P + k4 * 4];
    float4 a3 = *(const float4*)&sm[H1S_OFF + (rt2 * 4 + 3) * H1S_P + k4 * 4];
    float4 q0 = *(const float4*)&sm[W2S_OFF + ((k4 - 16) * 4 + 0) * H2_ + ct2 * 4];
    float4 q1 = *(const float4*)&sm[W2S_OFF + ((k4 - 16) * 4 + 1) * H2_ + ct2 * 4];
    float4 q2 = *(const float4*)&sm[W2S_OFF + ((k4 - 16) * 4 + 2) * H2_ + ct2 * 4];
    float4 q3 = *(const float4*)&sm[W2S_OFF + ((k4 - 16) * 4 + 3) * H2_ + ct2 * 4];
    fma4(acc2[0], a0.x, q0); fma4(acc2[0], a0.y, q1); fma4(acc2[0], a0.z, q2); fma4(acc2[0], a0.w, q3);
    fma4(acc2[1], a1.x, q0); fma4(acc2[1], a1.y, q1); fma4(acc2[1], a1.z, q2); fma4(acc2[1], a1.w, q3);
    fma4(acc2[2], a2.x, q0); fma4(acc2[2], a2.y, q1); fma4(acc2[2], a2.z, q2); fma4(acc2[2], a2.w, q3);
    fma4(acc2[3], a3.x, q0); fma4(acc2[3], a3.y, q1); fma4(acc2[3], a3.z, q2); fma4(acc2[3], a3.w, q3);
  }

  // ---- ReLU+b2 (regs); GEMM3 partials; butterfly over 16 col-groups ----
  float4 L[4];
  {
    float4 bb = ((const float4*)b2)[ct2];
    #pragma unroll
    for (int r = 0; r < 4; ++r) {
      float4 h = acc2[r];
      h.x = fmaxf(h.x + bb.x, 0.f); h.y = fmaxf(h.y + bb.y, 0.f);
      h.z = fmaxf(h.z + bb.z, 0.f); h.w = fmaxf(h.w + bb.w, 0.f);
      float4 t = make_float4(0.f, 0.f, 0.f, 0.f);
      fma4(t, h.x, w30); fma4(t, h.y, w31); fma4(t, h.z, w32); fma4(t, h.w, w33);
      L[r] = t;
    }
  }
  #pragma unroll
  for (int d = 1; d < 16; d <<= 1) {
    #pragma unroll
    for (int r = 0; r < 4; ++r) {
      L[r].x += __shfl_xor(L[r].x, d);
      L[r].y += __shfl_xor(L[r].y, d);
      L[r].z += __shfl_xor(L[r].z, d);
      L[r].w += __shfl_xor(L[r].w, d);
    }
  }

  // ---- softmax + dom/conf: lane ct2 (0..3) handles row rt2*4 + ct2 ----
  if (ct2 < 4) {
    float4 Lv = L[ct2];
    const int grow = row0 + rt2 * 4 + ct2;
    Lv.x += b3v.x; Lv.y += b3v.y; Lv.z += b3v.z; Lv.w += b3v.w;
    float mx = fmaxf(fmaxf(Lv.x, Lv.y), fmaxf(Lv.z, Lv.w));
    float e0 = expf(Lv.x - mx), e1 = expf(Lv.y - mx), e2 = expf(Lv.z - mx), e3 = expf(Lv.w - mx);
    float inv = 1.f / ((e0 + e1) + (e2 + e3));
    float p0 = e0 * inv, p1 = e1 * inv, p2 = e2 * inv, p3 = e3 * inv;
    *(float4*)&out[PROBS_OFF + (size_t)grow * 4] = make_float4(p0, p1, p2, p3);
    int dom = 0; float pm = p0;
    if (p1 > pm) { pm = p1; dom = 1; }
    if (p2 > pm) { pm = p2; dom = 2; }
    if (p3 > pm) { pm = p3; dom = 3; }
    out[MI_OFF + grow] = (float)dom;   // park dom for kernel 2
    out[MC_OFF + grow] = pm;           // park conf for kernel 2
  }
}

// ---- kernel 2: per-batch-row segmentation + segment means ----
__global__ __launch_bounds__(1024, 1) void seg_kernel(
    const float* __restrict__ inten, float* __restrict__ out)
{
  __shared__ float scnt[T_], ssi[T_], ssc[T_];
  __shared__ int wtot[16], wexcl[16];
  const int tid = threadIdx.x;
  const int lane = tid & 63, wid = tid >> 6;
  const size_t base = (size_t)blockIdx.x * T_;
  const float* tsS = out + TS_OFF;
  float* segO = out + SEG_OFF;
  float* miO  = out + MI_OFF;
  float* mcO  = out + MC_OFF;
  const int t4 = tid * 4;

  float4 dv = *(const float4*)&miO[base + t4];        // dom (as float)
  float4 tv = *(const float4*)&tsS[base + t4];        // transition scores
  float4 iv = *(const float4*)&inten[base + t4];      // intensity
  float4 cv = *(const float4*)&mcO[base + t4];        // confidence
  float pd = (tid == 0) ? 0.f : miO[base + t4 - 1];

  for (int i = tid; i < T_; i += 1024) { scnt[i] = 0.f; ssi[i] = 0.f; ssc[i] = 0.f; }

  int c0 = (t4 == 0) ? 0 : (((dv.x != pd)   || (tv.x > 0.7f)) ? 1 : 0);
  int c1 = ((dv.y != dv.x) || (tv.y > 0.7f)) ? 1 : 0;
  int c2 = ((dv.z != dv.y) || (tv.z > 0.7f)) ? 1 : 0;
  int c3 = ((dv.w != dv.z) || (tv.w > 0.7f)) ? 1 : 0;
  int l0 = c0, l1 = c0 + c1, l2 = l1 + c2, l3 = l2 + c3;
  const int tsum = l3;

  // wave-inclusive scan of per-thread sums
  int v = tsum;
  #pragma unroll
  for (int d = 1; d < 64; d <<= 1) {
    int o = __shfl_up(v, (unsigned)d);
    if (lane >= d) v += o;
  }
  if (lane == 63) wtot[wid] = v;
  __syncthreads();
  if (tid < 16) {
    int x = wtot[tid];
    int xx = x;
    #pragma unroll
    for (int d = 1; d < 16; d <<= 1) {
      int o = __shfl_up(xx, (unsigned)d);
      if (tid >= d) xx += o;
    }
    wexcl[tid] = xx - x;   // exclusive wave offset
  }
  __syncthreads();
  const int texcl = wexcl[wid] + (v - tsum);
  const int s0 = texcl + l0, s1 = texcl + l1, s2 = texcl + l2, s3 = texcl + l3;

  // merged LDS atomics for segment sums
  {
    int cur = s0; float aI = iv.x, aC = cv.x, aN = 1.f;
    if (s1 == cur) { aI += iv.y; aC += cv.y; aN += 1.f; }
    else { atomicAdd(&ssi[cur], aI); atomicAdd(&ssc[cur], aC); atomicAdd(&scnt[cur], aN);
           cur = s1; aI = iv.y; aC = cv.y; aN = 1.f; }
    if (s2 == cur) { aI += iv.z; aC += cv.z; aN += 1.f; }
    else { atomicAdd(&ssi[cur], aI); atomicAdd(&ssc[cur], aC); atomicAdd(&scnt[cur], aN);
           cur = s2; aI = iv.z; aC = cv.z; aN = 1.f; }
    if (s3 == cur) { aI += iv.w; aC += cv.w; aN += 1.f; }
    else { atomicAdd(&ssi[cur], aI); atomicAdd(&ssc[cur], aC); atomicAdd(&scnt[cur], aN);
           cur = s3; aI = iv.w; aC = cv.w; aN = 1.f; }
    atomicAdd(&ssi[cur], aI); atomicAdd(&ssc[cur], aC); atomicAdd(&scnt[cur], aN);
  }
  __syncthreads();

  float n0 = scnt[s0], n1 = scnt[s1], n2 = scnt[s2], n3 = scnt[s3];
  float4 m4, q4, g4;
  m4.x = ssi[s0] / n0; m4.y = ssi[s1] / n1; m4.z = ssi[s2] / n2; m4.w = ssi[s3] / n3;
  q4.x = ssc[s0] / n0; q4.y = ssc[s1] / n1; q4.z = ssc[s2] / n2; q4.w = ssc[s3] / n3;
  g4.x = (float)s0; g4.y = (float)s1; g4.z = (float)s2; g4.w = (float)s3;
  *(float4*)&segO[base + t4] = g4;
  *(float4*)&miO[base + t4]  = m4;
  *(float4*)&mcO[base + t4]  = q4;
}

extern "C" void kernel_launch(void* const* d_in, const int* in_sizes, int n_in,
                              void* d_out, int out_size, void* d_ws, size_t ws_size,
                              hipStream_t stream) {
  (void)in_sizes; (void)n_in; (void)out_size; (void)d_ws; (void)ws_size;
  const float* X   = (const float*)d_in[0];
  const float* INT = (const float*)d_in[1];
  const float* W1  = (const float*)d_in[2];
  const float* B1  = (const float*)d_in[3];
  const float* W2  = (const float*)d_in[4];
  const float* B2  = (const float*)d_in[5];
  const float* W3  = (const float*)d_in[6];
  const float* B3  = (const float*)d_in[7];
  const float* CW  = (const float*)d_in[8];
  const float* CB  = (const float*)d_in[9];
  float* out = (float*)d_out;

  hipLaunchKernelGGL(mlp_conv_kernel, dim3(R_ / TB), dim3(256), 0, stream,
                     X, W1, B1, W2, B2, W3, B3, CW, CB, out);
  hipLaunchKernelGGL(seg_kernel, dim3(B_), dim3(1024), 0, stream, INT, out);
}